// Round 1
// 693.769 us; speedup vs baseline: 1.1342x; 1.1342x over previous
//
#include <hip/hip_runtime.h>
#include <stdint.h>

#define HW    16384
#define NB    64
#define W2    130           // padded spatial dim (1-px halo each side)
#define PXS   (W2*W2)       // 16900 pixels per padded plane
#define WQH   70144         // fp16 weight halves per sample (frag-ordered)
#define EPSB  1e-5f

typedef _Float16 h8  __attribute__((ext_vector_type(8)));
typedef _Float16 h4  __attribute__((ext_vector_type(4)));
typedef float    f16v __attribute__((ext_vector_type(16)));
typedef float    f4  __attribute__((ext_vector_type(4)));
typedef h8 uh8 __attribute__((aligned(4)));
typedef h4 uh4 __attribute__((aligned(4)));
typedef f4 uf4 __attribute__((aligned(4)));

// ---------------------------------------------------------------------------
// prep_w: gather per-sample hypernet weights, fold BN scale, convert fp16,
// and write in EXACT mfma_32x32x16_f16 A-fragment order:
//   per layer, frame f = (tap*KST + kstep); within frame, lane(0..63) holds
//   8 halves: w[co = lane&31][c = kstep*16 + (lane>>5)*8 + e]  (0-padded).
// One thread produces one lane-frag (8 halves, one 16B store).
// Frames/layer: L0-2: 9, L3-8: 18, L9(1x1): 2. Frag offsets FO[] below.
// Also emits fp32 bias[l*32+co] = beta - mu*scale (0 for padded co / L9).
// ---------------------------------------------------------------------------
__global__ void prep_w(const float* __restrict__ w1, const float* __restrict__ w2,
                       const float* __restrict__ w3, const float* __restrict__ w4,
                       const float* __restrict__ g,  const float* __restrict__ be,
                       const float* __restrict__ mu, const float* __restrict__ va,
                       _Float16* __restrict__ wq, float* __restrict__ bias)
{
    const int FO[11]   = {0,576,1152,1728,2880,4032,5184,6336,7488,8640,8768};
    const int start[10]= {0,1080,2376,3672,8424,13608,16200,20952,26136,28728};
    const int COt[10]  = {12,12,12,24,24,12,24,24,12,11};
    const int CIt[10]  = {10,12,12,22,24,24,22,24,24,22};
    const int bnoff[10]= {0,12,24,36,60,84,96,120,144,0};
    const int KST[10]  = {1,1,1,2,2,2,2,2,2,2};

    long tid = (long)blockIdx.x * 256 + threadIdx.x;
    long total = (long)NB * 8768, stride = (long)gridDim.x * 256;
    for (long idx = tid; idx < total; idx += stride) {
        int b = (int)(idx / 8768), i = (int)(idx - (long)b * 8768);
        int l = 9; while (i < FO[l]) --l;
        int j = i - FO[l];
        int f = j >> 6, lane = j & 63;
        int ks = (KST[l] == 2) ? (f & 1) : 0;
        int s  = (KST[l] == 2) ? (f >> 1) : f;      // 3x3 tap index (0 for L9)
        int co = lane & 31, hi = lane >> 5;
        int CO = COt[l], CI = CIt[l];
        float scale = 1.f;
        if (l < 9 && co < CO) {
            int bi = bnoff[l] + co;
            scale = g[bi] * rsqrtf(va[bi] + EPSB);
        }
        int c0 = ks * 16 + hi * 8;
        __attribute__((aligned(16))) _Float16 vals[8];
#pragma unroll
        for (int e = 0; e < 8; ++e) {
            int c = c0 + e; float wv = 0.f;
            if (co < CO && c < CI) {
                int p = (l < 9) ? start[l] + (co * CI + c) * 9 + s
                                : start[9] + co * CI + c;
                const float* src; long si;
                if      (p <  3672) { src = w1; si = (long)b *  3672 + p; }
                else if (p < 16200) { src = w2; si = (long)b * 12528 + (p -  3672); }
                else if (p < 28728) { src = w3; si = (long)b * 12528 + (p - 16200); }
                else                { src = w4; si = (long)b *   242 + (p - 28728); }
                wv = src[si] * scale;
            }
            vals[e] = (_Float16)wv;
        }
        *(uh8*)(wq + idx * 8) = *(const h8*)vals;
    }
    if (tid < 320) {
        int l = (int)tid >> 5, co = (int)tid & 31;
        float v = 0.f;
        if (l < 9 && co < COt[l]) {
            int bi = bnoff[l] + co;
            float sc = g[bi] * rsqrtf(va[bi] + EPSB);
            v = be[bi] - mu[bi] * sc;
        }
        bias[tid] = v;
    }
}

// ---------------------------------------------------------------------------
// pad_x: fill the skip buffer bufS (NHWC, 32 fp16 ch/px, 130x130) for a chunk:
// channels 12..21 = x (fp16), everything else (incl. borders) = 0.
// Conv layers later overwrite only ch 0..11 interior, so x + zero-padding
// persist; dense-skip concat becomes "read bufS with 22 real channels".
// ---------------------------------------------------------------------------
__global__ void pad_x(const float* __restrict__ x, _Float16* __restrict__ bufS, int b0)
{
    int sl = blockIdx.x >> 3, part = blockIdx.x & 7;
    int gb = b0 + sl;
    const float* __restrict__ xs = x + (long)gb * 10 * HW;
    _Float16* __restrict__ d = bufS + (long)sl * PXS * 32;
    for (int p = part * 256 + threadIdx.x; p < PXS; p += 2048) {
        int r = p / W2, cc = p - r * W2;
        __attribute__((aligned(16))) _Float16 px[32];
#pragma unroll
        for (int i = 0; i < 32; ++i) px[i] = (_Float16)0.f;
        if (r >= 1 && r <= 128 && cc >= 1 && cc <= 128) {
            int so = (r - 1) * 128 + (cc - 1);
#pragma unroll
            for (int c = 0; c < 10; ++c)
                px[12 + c] = (_Float16)xs[c * HW + so];
        }
        _Float16* dp = d + (long)p * 32;
        *(uh8*)(dp)      = *(const h8*)(px);
        *(uh8*)(dp + 8)  = *(const h8*)(px + 8);
        *(uh8*)(dp + 16) = *(const h8*)(px + 16);
        *(uh8*)(dp + 24) = *(const h8*)(px + 24);
    }
}

// ---- zero the 1-px spatial borders of the ping-pong buffers (interiors are
// fully overwritten by every conv, incl. padded channels via zero bias).
__global__ void zero_b(_Float16* __restrict__ b16A, _Float16* __restrict__ b16B,
                       _Float16* __restrict__ b32A, _Float16* __restrict__ b32B)
{
    int sl = blockIdx.x;
    _Float16* pA = b16A + (long)sl * PXS * 16;
    _Float16* pB = b16B + (long)sl * PXS * 16;
    _Float16* pC = b32A + (long)sl * PXS * 32;
    _Float16* pD = b32B + (long)sl * PXS * 32;
    h8 z = {};
    for (int j = threadIdx.x; j < 516; j += 256) {
        int p;
        if      (j < 130) p = j;
        else if (j < 260) p = 129 * W2 + (j - 130);
        else { int k = j - 260; p = (1 + (k >> 1)) * W2 + ((k & 1) ? 129 : 0); }
        *(uh8*)(pA + (long)p * 16) = z; *(uh8*)(pA + (long)p * 16 + 8) = z;
        *(uh8*)(pB + (long)p * 16) = z; *(uh8*)(pB + (long)p * 16 + 8) = z;
#pragma unroll
        for (int q = 0; q < 4; ++q) {
            *(uh8*)(pC + (long)p * 32 + q * 8) = z;
            *(uh8*)(pD + (long)p * 32 + q * 8) = z;
        }
    }
}

// ---------------------------------------------------------------------------
// conv3: 3x3 per-sample conv as 9 shift-GEMMs on v_mfma_f32_32x32x16_f16.
//   A (M=32=co):  preloaded weight frags, lane%32 = co, lane/32 = k-half.
//   B (N=32=px):  one 16B NHWC load per MFMA: lane%32 = pixel column,
//                 lane/32 selects 8-ch half; KST k-steps cover CIN<=32.
//   D: col=lane&31 (px), row=(r&3)+8*(r>>2)+4*(lane>>5) (co)  [HW-verified].
// Block = 4 waves; wave owns 8 consecutive rows x one 32-px column block
// (NPB=8 amortizes the A-frag load 8x and gives vertical-halo L1 reuse).
// Epilogue: +bias, ReLU, cvt fp16, store co-chunks of 4 (NHWC).
// CPIN/CPOUT are BYTES per pixel (32 = 16ch, 64 = 32ch). LIM12: write only
// co<12 (skip buffer - must not clobber x at ch 12..21).
// ---------------------------------------------------------------------------
template<int CPIN, int CHOFF, int KST, int CPOUT, int LIM12>
__global__ __launch_bounds__(256, 2)
void conv3(const _Float16* __restrict__ in, _Float16* __restrict__ out,
           const _Float16* __restrict__ wq, int loff,
           const float* __restrict__ bias, int boff, int b0)
{
    constexpr int FR = 9 * KST;
    const int s  = blockIdx.y, gb = b0 + s;
    const int t  = threadIdx.x;
    const int w  = t >> 6, l = t & 63;
    const int lo5 = l & 31, hi = l >> 5;
    const int cb  = blockIdx.x & 3;
    const int y00 = (blockIdx.x >> 2) * 32 + w * 8;
    const int xpix = cb * 32 + lo5;                 // interior x: 0..127

    // A fragments (reused across 8 row-blocks)
    const _Float16* wl = wq + (long)gb * WQH + loff + (long)l * 8;
    h8 afr[FR];
#pragma unroll
    for (int f = 0; f < FR; ++f) afr[f] = *(const uh8*)(wl + (long)f * 512);

    // bias chunks: chunk q covers co = 8q + 4*hi + 0..3
    f4 bv[4];
#pragma unroll
    for (int q = 0; q < 4; ++q) bv[q] = *(const uf4*)(bias + boff + hi * 4 + q * 8);

    const _Float16* ib = in + (long)s * PXS * (CPIN / 2);
    _Float16* ob = out + (long)s * PXS * (CPOUT / 2);

#pragma unroll 1
    for (int tt = 0; tt < 8; ++tt) {
        int y = y00 + tt;                           // interior row: 0..127
        // input rows y..y+2 (padded coords), cols xpix..xpix+2 via imm offsets
        const char* r0 = (const char*)ib + ((long)y * W2 + xpix) * CPIN + CHOFF + hi * 16;
        const char* r1 = r0 + (long)W2 * CPIN;
        const char* r2 = r1 + (long)W2 * CPIN;

        h8 bf[FR];
        {
            int f = 0;
#pragma unroll
            for (int kr = 0; kr < 3; ++kr) {
                const char* rp = (kr == 0) ? r0 : (kr == 1) ? r1 : r2;
#pragma unroll
                for (int kc = 0; kc < 3; ++kc)
#pragma unroll
                    for (int ks = 0; ks < KST; ++ks) {
                        bf[f] = *(const uh8*)(rp + kc * CPIN + ks * 32);
                        ++f;
                    }
            }
        }
        f16v acc = {};
#pragma unroll
        for (int f = 0; f < FR; ++f)
            acc = __builtin_amdgcn_mfma_f32_32x32x16_f16(afr[f], bf[f], acc, 0, 0, 0);

        // epilogue: bias + ReLU + fp16 store (NHWC)
        _Float16* op = ob + ((long)(y + 1) * W2 + (xpix + 1)) * (CPOUT / 2);
        constexpr int QN = (CPOUT == 32) ? 2 : (LIM12 ? 2 : 4);
#pragma unroll
        for (int q = 0; q < QN; ++q) {
            if (LIM12 && q == 1 && hi) continue;    // co 12..15: keep x channels
            float v0 = fmaxf(acc[4 * q + 0] + bv[q][0], 0.f);
            float v1 = fmaxf(acc[4 * q + 1] + bv[q][1], 0.f);
            float v2 = fmaxf(acc[4 * q + 2] + bv[q][2], 0.f);
            float v3 = fmaxf(acc[4 * q + 3] + bv[q][3], 0.f);
            h4 hv = { (_Float16)v0, (_Float16)v1, (_Float16)v2, (_Float16)v3 };
            *(uh4*)(op + 8 * q + 4 * hi) = hv;
        }
    }
}

// ---- final 1x1 conv (CIN=22 in bufS, CO=11), fp32 NCHW output, no BN/ReLU.
__global__ __launch_bounds__(256, 2)
void conv1(const _Float16* __restrict__ in, float* __restrict__ outF,
           const _Float16* __restrict__ wq, int loff, int b0)
{
    const int s = blockIdx.y, gb = b0 + s;
    const int t = threadIdx.x, w = t >> 6, l = t & 63;
    const int lo5 = l & 31, hi = l >> 5;
    const int cb = blockIdx.x & 3;
    const int y00 = (blockIdx.x >> 2) * 32 + w * 8;
    const int xpix = cb * 32 + lo5;

    const _Float16* wl = wq + (long)gb * WQH + loff + (long)l * 8;
    h8 a0 = *(const uh8*)(wl);
    h8 a1 = *(const uh8*)(wl + 512);
    const _Float16* ib = in + (long)s * PXS * 32;

#pragma unroll 1
    for (int tt = 0; tt < 8; ++tt) {
        int y = y00 + tt;
        const _Float16* bp = ib + ((long)(y + 1) * W2 + xpix + 1) * 32 + hi * 8;
        h8 bA = *(const uh8*)(bp);
        h8 bB = *(const uh8*)(bp + 16);
        f16v acc = {};
        acc = __builtin_amdgcn_mfma_f32_32x32x16_f16(a0, bA, acc, 0, 0, 0);
        acc = __builtin_amdgcn_mfma_f32_32x32x16_f16(a1, bB, acc, 0, 0, 0);
        long px = (long)y * 128 + xpix;
#pragma unroll
        for (int r = 0; r < 16; ++r) {
            int co = (r & 3) + 8 * (r >> 2) + 4 * hi;
            if (co < 11) outF[((long)gb * 11 + co) * HW + px] = acc[r];
        }
    }
}

extern "C" void kernel_launch(void* const* d_in, const int* in_sizes, int n_in,
                              void* d_out, int out_size, void* d_ws, size_t ws_size,
                              hipStream_t stream)
{
    const float *x = (const float*)d_in[0], *w1 = (const float*)d_in[1],
                *w2 = (const float*)d_in[2], *w3 = (const float*)d_in[3],
                *w4 = (const float*)d_in[4], *g  = (const float*)d_in[5],
                *be = (const float*)d_in[6], *mu = (const float*)d_in[7],
                *va = (const float*)d_in[8];
    if (n_in == 9) {   // identify by size signature (fallback: dict order)
        const float* big801[2] = {nullptr, nullptr}; int n801 = 0;
        const float* bn156[4]  = {nullptr, nullptr, nullptr, nullptr}; int n156 = 0;
        const float *fx = nullptr, *fw1 = nullptr, *fw4 = nullptr;
        for (int i = 0; i < 9; ++i) {
            int sz = in_sizes[i];
            if      (sz == 10485760) fx  = (const float*)d_in[i];
            else if (sz ==   235008) fw1 = (const float*)d_in[i];
            else if (sz ==   801792) { if (n801 < 2) big801[n801++] = (const float*)d_in[i]; }
            else if (sz ==    15488) fw4 = (const float*)d_in[i];
            else if (sz ==      156) { if (n156 < 4) bn156[n156++] = (const float*)d_in[i]; }
        }
        if (fx && fw1 && fw4 && n801 == 2 && n156 == 4) {
            x = fx; w1 = fw1; w2 = big801[0]; w3 = big801[1]; w4 = fw4;
            g = bn156[0]; be = bn156[1]; mu = bn156[2]; va = bn156[3];
        }
    }
    float* out = (float*)d_out;

    // ws: [wq fp16 8.98MB][bias 2KB][bufS | b16A | b16B | b32A | b32B] x chunk
    const size_t wqB   = (size_t)NB * WQH * 2;
    const size_t biasB = 2048;
    const size_t hdr   = wqB + biasB;
    const size_t perSlot = (size_t)PXS * 2 * (32 + 16 + 16 + 32 + 32); // 4.33MB
    size_t avail = ws_size > hdr ? ws_size - hdr : 0;
    int chunk = (int)(avail / perSlot);
    if (chunk > NB) chunk = NB;
    if (chunk < 1)  chunk = 1;

    _Float16* wq   = (_Float16*)d_ws;
    float*    bias = (float*)((char*)d_ws + wqB);
    _Float16* bufS = (_Float16*)((char*)d_ws + hdr);
    _Float16* b16A = bufS + (size_t)chunk * PXS * 32;
    _Float16* b16B = b16A + (size_t)chunk * PXS * 16;
    _Float16* b32A = b16B + (size_t)chunk * PXS * 16;
    _Float16* b32B = b32A + (size_t)chunk * PXS * 32;

    prep_w<<<2048, 256, 0, stream>>>(w1, w2, w3, w4, g, be, mu, va, wq, bias);

    for (int b0 = 0; b0 < NB; b0 += chunk) {
        int nb = (NB - b0 < chunk) ? (NB - b0) : chunk;
        pad_x <<<nb * 8, 256, 0, stream>>>(x, bufS, b0);
        zero_b<<<nb,     256, 0, stream>>>(b16A, b16B, b32A, b32B);
        dim3 gc(16, nb);
        // weight frag-offsets (halves): see prep FO[]*8; bias offsets l*32
        conv3<64,24,1,32,0><<<gc,256,0,stream>>>(bufS, b16A, wq,     0, bias,   0, b0); // L0 10->12 (x @ch12)
        conv3<32, 0,1,32,0><<<gc,256,0,stream>>>(b16A, b16B, wq,  4608, bias,  32, b0); // L1 12->12
        conv3<32, 0,1,64,1><<<gc,256,0,stream>>>(b16B, bufS, wq,  9216, bias,  64, b0); // L2 12->12 -> skip ch0-11
        conv3<64, 0,2,64,0><<<gc,256,0,stream>>>(bufS, b32A, wq, 13824, bias,  96, b0); // L3 22->24
        conv3<64, 0,2,64,0><<<gc,256,0,stream>>>(b32A, b32B, wq, 23040, bias, 128, b0); // L4 24->24
        conv3<64, 0,2,64,1><<<gc,256,0,stream>>>(b32B, bufS, wq, 32256, bias, 160, b0); // L5 24->12 -> skip
        conv3<64, 0,2,64,0><<<gc,256,0,stream>>>(bufS, b32A, wq, 41472, bias, 192, b0); // L6 22->24
        conv3<64, 0,2,64,0><<<gc,256,0,stream>>>(b32A, b32B, wq, 50688, bias, 224, b0); // L7 24->24
        conv3<64, 0,2,64,1><<<gc,256,0,stream>>>(b32B, bufS, wq, 59904, bias, 256, b0); // L8 24->12 -> skip
        conv1<<<gc,256,0,stream>>>(bufS, out, wq, 69120, b0);                           // L9 1x1 22->11
    }
}

// Round 2
// 599.148 us; speedup vs baseline: 1.3134x; 1.1579x over previous
//
#include <hip/hip_runtime.h>
#include <stdint.h>

#define HW    16384
#define NB    64
#define W2    130           // padded spatial dim (1-px halo each side)
#define PXS   (W2*W2)       // 16900 pixels per padded plane
#define WQH   70144         // fp16 weight halves per sample (frag-ordered)
#define EPSB  1e-5f

typedef _Float16 h8  __attribute__((ext_vector_type(8)));
typedef _Float16 h4  __attribute__((ext_vector_type(4)));
typedef float    f16v __attribute__((ext_vector_type(16)));
typedef float    f4  __attribute__((ext_vector_type(4)));
typedef h8 uh8 __attribute__((aligned(4)));
typedef h4 uh4 __attribute__((aligned(4)));
typedef f4 uf4 __attribute__((aligned(4)));

// ---------------------------------------------------------------------------
// prep_w: gather per-sample hypernet weights, fold BN scale, convert fp16,
// and write in EXACT mfma_32x32x16_f16 A-fragment order:
//   per layer, frame f = (tap*KST + kstep); within frame, lane(0..63) holds
//   8 halves: w[co = lane&31][c = kstep*16 + (lane>>5)*8 + e]  (0-padded).
// One thread produces one lane-frag (8 halves, one 16B store).
// Frames/layer: L0-2: 9, L3-8: 18, L9(1x1): 2. Frag offsets FO[] below.
// Also emits fp32 bias[l*32+co] = beta - mu*scale (0 for padded co / L9).
// ---------------------------------------------------------------------------
__global__ void prep_w(const float* __restrict__ w1, const float* __restrict__ w2,
                       const float* __restrict__ w3, const float* __restrict__ w4,
                       const float* __restrict__ g,  const float* __restrict__ be,
                       const float* __restrict__ mu, const float* __restrict__ va,
                       _Float16* __restrict__ wq, float* __restrict__ bias)
{
    const int FO[11]   = {0,576,1152,1728,2880,4032,5184,6336,7488,8640,8768};
    const int start[10]= {0,1080,2376,3672,8424,13608,16200,20952,26136,28728};
    const int COt[10]  = {12,12,12,24,24,12,24,24,12,11};
    const int CIt[10]  = {10,12,12,22,24,24,22,24,24,22};
    const int bnoff[10]= {0,12,24,36,60,84,96,120,144,0};
    const int KST[10]  = {1,1,1,2,2,2,2,2,2,2};

    long tid = (long)blockIdx.x * 256 + threadIdx.x;
    long total = (long)NB * 8768, stride = (long)gridDim.x * 256;
    for (long idx = tid; idx < total; idx += stride) {
        int b = (int)(idx / 8768), i = (int)(idx - (long)b * 8768);
        int l = 9; while (i < FO[l]) --l;
        int j = i - FO[l];
        int f = j >> 6, lane = j & 63;
        int ks = (KST[l] == 2) ? (f & 1) : 0;
        int s  = (KST[l] == 2) ? (f >> 1) : f;      // 3x3 tap index (0 for L9)
        int co = lane & 31, hi = lane >> 5;
        int CO = COt[l], CI = CIt[l];
        float scale = 1.f;
        if (l < 9 && co < CO) {
            int bi = bnoff[l] + co;
            scale = g[bi] * rsqrtf(va[bi] + EPSB);
        }
        int c0 = ks * 16 + hi * 8;
        __attribute__((aligned(16))) _Float16 vals[8];
#pragma unroll
        for (int e = 0; e < 8; ++e) {
            int c = c0 + e; float wv = 0.f;
            if (co < CO && c < CI) {
                int p = (l < 9) ? start[l] + (co * CI + c) * 9 + s
                                : start[9] + co * CI + c;
                const float* src; long si;
                if      (p <  3672) { src = w1; si = (long)b *  3672 + p; }
                else if (p < 16200) { src = w2; si = (long)b * 12528 + (p -  3672); }
                else if (p < 28728) { src = w3; si = (long)b * 12528 + (p - 16200); }
                else                { src = w4; si = (long)b *   242 + (p - 28728); }
                wv = src[si] * scale;
            }
            vals[e] = (_Float16)wv;
        }
        *(uh8*)(wq + idx * 8) = *(const h8*)vals;
    }
    if (tid < 320) {
        int l = (int)tid >> 5, co = (int)tid & 31;
        float v = 0.f;
        if (l < 9 && co < COt[l]) {
            int bi = bnoff[l] + co;
            float sc = g[bi] * rsqrtf(va[bi] + EPSB);
            v = be[bi] - mu[bi] * sc;
        }
        bias[tid] = v;
    }
}

// ---------------------------------------------------------------------------
// pad_x: fill the skip buffer bufS (NHWC, 32 fp16 ch/px, 130x130) for a chunk:
// channels 12..21 = x (fp16), everything else (incl. borders) = 0.
// Conv layers later overwrite only ch 0..11 interior, so x + zero-padding
// persist; dense-skip concat becomes "read bufS with 22 real channels".
// ---------------------------------------------------------------------------
__global__ void pad_x(const float* __restrict__ x, _Float16* __restrict__ bufS, int b0)
{
    int sl = blockIdx.x >> 3, part = blockIdx.x & 7;
    int gb = b0 + sl;
    const float* __restrict__ xs = x + (long)gb * 10 * HW;
    _Float16* __restrict__ d = bufS + (long)sl * PXS * 32;
    for (int p = part * 256 + threadIdx.x; p < PXS; p += 2048) {
        int r = p / W2, cc = p - r * W2;
        __attribute__((aligned(16))) _Float16 px[32];
#pragma unroll
        for (int i = 0; i < 32; ++i) px[i] = (_Float16)0.f;
        if (r >= 1 && r <= 128 && cc >= 1 && cc <= 128) {
            int so = (r - 1) * 128 + (cc - 1);
#pragma unroll
            for (int c = 0; c < 10; ++c)
                px[12 + c] = (_Float16)xs[c * HW + so];
        }
        _Float16* dp = d + (long)p * 32;
        *(uh8*)(dp)      = *(const h8*)(px);
        *(uh8*)(dp + 8)  = *(const h8*)(px + 8);
        *(uh8*)(dp + 16) = *(const h8*)(px + 16);
        *(uh8*)(dp + 24) = *(const h8*)(px + 24);
    }
}

// ---- zero the 1-px spatial borders of the ping-pong buffers. Runs ONCE:
// conv3 stores interior-only, so borders are never re-dirtied across chunks.
__global__ void zero_b(_Float16* __restrict__ b16A, _Float16* __restrict__ b16B,
                       _Float16* __restrict__ b32A, _Float16* __restrict__ b32B)
{
    int sl = blockIdx.x;
    _Float16* pA = b16A + (long)sl * PXS * 16;
    _Float16* pB = b16B + (long)sl * PXS * 16;
    _Float16* pC = b32A + (long)sl * PXS * 32;
    _Float16* pD = b32B + (long)sl * PXS * 32;
    h8 z = {};
    for (int j = threadIdx.x; j < 516; j += 256) {
        int p;
        if      (j < 130) p = j;
        else if (j < 260) p = 129 * W2 + (j - 130);
        else { int k = j - 260; p = (1 + (k >> 1)) * W2 + ((k & 1) ? 129 : 0); }
        *(uh8*)(pA + (long)p * 16) = z; *(uh8*)(pA + (long)p * 16 + 8) = z;
        *(uh8*)(pB + (long)p * 16) = z; *(uh8*)(pB + (long)p * 16 + 8) = z;
#pragma unroll
        for (int q = 0; q < 4; ++q) {
            *(uh8*)(pC + (long)p * 32 + q * 8) = z;
            *(uh8*)(pD + (long)p * 32 + q * 8) = z;
        }
    }
}

// ---------------------------------------------------------------------------
// conv3: 3x3 per-sample conv as 9 shift-GEMMs on v_mfma_f32_32x32x16_f16.
// Loop nest (round-2 restructure, latency-bound fix):
//   wave tile = 4 output rows x 32 px. Group-major over (kc,ks):
//     load 6-row B window bf[6] (9 taps share rows vertically),
//     then for kr=0..2: load ONE A-frag (4 VGPR, never demoted),
//       4 independent MFMAs acc[tt] += A * bf[kr+tt].
//   => 12 MFMAs per 9 loads, 4-way MFMA ILP, no 18-deep serial acc chain.
// 1D grid nb*32 with XCD swizzle: all 32 blocks of a sample land on one XCD
// (4 samples/XCD ~= 4.3MB input ~ L2-resident).
// Epilogue: +bias, ReLU, cvt fp16, store co-chunks of 4 (NHWC).
// CPIN/CPOUT are BYTES per pixel (32 = 16ch, 64 = 32ch). LIM12: write only
// co<12 (skip buffer - must not clobber x at ch 12..21).
// ---------------------------------------------------------------------------
template<int CPIN, int CHOFF, int KST, int CPOUT, int LIM12>
__global__ __launch_bounds__(256, 3)
void conv3(const _Float16* __restrict__ in, _Float16* __restrict__ out,
           const _Float16* __restrict__ wq, int loff,
           const float* __restrict__ bias, int boff, int b0)
{
    const int t  = threadIdx.x;
    const int w  = t >> 6, l = t & 63;
    const int lo5 = l & 31, hi = l >> 5;

    const int nb = (int)(gridDim.x >> 5);
    int s, tile;
    if ((nb & 7) == 0) {                      // XCD-localize each sample
        int xcd = (int)(blockIdx.x & 7);
        int j   = (int)(blockIdx.x >> 3);
        s    = xcd * (nb >> 3) + (j >> 5);
        tile = j & 31;
    } else { s = (int)(blockIdx.x >> 5); tile = (int)(blockIdx.x & 31); }
    const int gb = b0 + s;
    const int cb   = tile & 3;
    const int y0   = (tile >> 2) * 16 + w * 4;   // interior row base 0..124
    const int xpix = cb * 32 + lo5;              // interior col 0..127

    const _Float16* wl = wq + (long)gb * WQH + loff + (long)l * 8;

    // bias chunks: chunk q covers co = 8q + 4*hi + 0..3
    f4 bv[4];
#pragma unroll
    for (int q = 0; q < 4; ++q) bv[q] = *(const uf4*)(bias + boff + hi * 4 + q * 8);

    // 6 input row pointers (padded rows y0 .. y0+5)
    const char* ibb = (const char*)in + (long)s * PXS * CPIN
                    + (long)xpix * CPIN + CHOFF + hi * 16;
    const char* rp[6];
#pragma unroll
    for (int r = 0; r < 6; ++r) rp[r] = ibb + (long)(y0 + r) * W2 * CPIN;

    f16v acc[4];
    {
        f16v z = {};
#pragma unroll
        for (int i = 0; i < 4; ++i) acc[i] = z;
    }

#pragma unroll
    for (int g = 0; g < 3 * KST; ++g) {
        const int kc = g / KST, ks = g - kc * KST;
        h8 bf[6];
#pragma unroll
        for (int r = 0; r < 6; ++r)
            bf[r] = *(const uh8*)(rp[r] + kc * CPIN + ks * 32);
#pragma unroll
        for (int kr = 0; kr < 3; ++kr) {
            h8 af = *(const uh8*)(wl + ((kr * 3 + kc) * KST + ks) * 512);
#pragma unroll
            for (int tt = 0; tt < 4; ++tt)
                acc[tt] = __builtin_amdgcn_mfma_f32_32x32x16_f16(af, bf[kr + tt], acc[tt], 0, 0, 0);
        }
    }

    // epilogue: bias + ReLU + fp16 store (NHWC)
    _Float16* ob = out + (long)s * PXS * (CPOUT / 2);
#pragma unroll
    for (int tt = 0; tt < 4; ++tt) {
        int y = y0 + tt;
        _Float16* op = ob + ((long)(y + 1) * W2 + (xpix + 1)) * (CPOUT / 2);
        constexpr int QN = (CPOUT == 32) ? 2 : (LIM12 ? 2 : 4);
#pragma unroll
        for (int q = 0; q < QN; ++q) {
            if (LIM12 && q == 1 && hi) continue;    // co 12..15: keep x channels
            float v0 = fmaxf(acc[tt][4 * q + 0] + bv[q][0], 0.f);
            float v1 = fmaxf(acc[tt][4 * q + 1] + bv[q][1], 0.f);
            float v2 = fmaxf(acc[tt][4 * q + 2] + bv[q][2], 0.f);
            float v3 = fmaxf(acc[tt][4 * q + 3] + bv[q][3], 0.f);
            h4 hv = { (_Float16)v0, (_Float16)v1, (_Float16)v2, (_Float16)v3 };
            *(uh4*)(op + 8 * q + 4 * hi) = hv;
        }
    }
}

// ---- final 1x1 conv (CIN=22 in bufS, CO=11), fp32 NCHW output, no BN/ReLU.
__global__ __launch_bounds__(256, 2)
void conv1(const _Float16* __restrict__ in, float* __restrict__ outF,
           const _Float16* __restrict__ wq, int loff, int b0)
{
    const int s = blockIdx.y, gb = b0 + s;
    const int t = threadIdx.x, w = t >> 6, l = t & 63;
    const int lo5 = l & 31, hi = l >> 5;
    const int cb = blockIdx.x & 3;
    const int y00 = (blockIdx.x >> 2) * 32 + w * 8;
    const int xpix = cb * 32 + lo5;

    const _Float16* wl = wq + (long)gb * WQH + loff + (long)l * 8;
    h8 a0 = *(const uh8*)(wl);
    h8 a1 = *(const uh8*)(wl + 512);
    const _Float16* ib = in + (long)s * PXS * 32;

#pragma unroll 1
    for (int tt = 0; tt < 8; ++tt) {
        int y = y00 + tt;
        const _Float16* bp = ib + ((long)(y + 1) * W2 + xpix + 1) * 32 + hi * 8;
        h8 bA = *(const uh8*)(bp);
        h8 bB = *(const uh8*)(bp + 16);
        f16v acc = {};
        acc = __builtin_amdgcn_mfma_f32_32x32x16_f16(a0, bA, acc, 0, 0, 0);
        acc = __builtin_amdgcn_mfma_f32_32x32x16_f16(a1, bB, acc, 0, 0, 0);
        long px = (long)y * 128 + xpix;
#pragma unroll
        for (int r = 0; r < 16; ++r) {
            int co = (r & 3) + 8 * (r >> 2) + 4 * hi;
            if (co < 11) outF[((long)gb * 11 + co) * HW + px] = acc[r];
        }
    }
}

extern "C" void kernel_launch(void* const* d_in, const int* in_sizes, int n_in,
                              void* d_out, int out_size, void* d_ws, size_t ws_size,
                              hipStream_t stream)
{
    const float *x = (const float*)d_in[0], *w1 = (const float*)d_in[1],
                *w2 = (const float*)d_in[2], *w3 = (const float*)d_in[3],
                *w4 = (const float*)d_in[4], *g  = (const float*)d_in[5],
                *be = (const float*)d_in[6], *mu = (const float*)d_in[7],
                *va = (const float*)d_in[8];
    if (n_in == 9) {   // identify by size signature (fallback: dict order)
        const float* big801[2] = {nullptr, nullptr}; int n801 = 0;
        const float* bn156[4]  = {nullptr, nullptr, nullptr, nullptr}; int n156 = 0;
        const float *fx = nullptr, *fw1 = nullptr, *fw4 = nullptr;
        for (int i = 0; i < 9; ++i) {
            int sz = in_sizes[i];
            if      (sz == 10485760) fx  = (const float*)d_in[i];
            else if (sz ==   235008) fw1 = (const float*)d_in[i];
            else if (sz ==   801792) { if (n801 < 2) big801[n801++] = (const float*)d_in[i]; }
            else if (sz ==    15488) fw4 = (const float*)d_in[i];
            else if (sz ==      156) { if (n156 < 4) bn156[n156++] = (const float*)d_in[i]; }
        }
        if (fx && fw1 && fw4 && n801 == 2 && n156 == 4) {
            x = fx; w1 = fw1; w2 = big801[0]; w3 = big801[1]; w4 = fw4;
            g = bn156[0]; be = bn156[1]; mu = bn156[2]; va = bn156[3];
        }
    }
    float* out = (float*)d_out;

    // ws: [wq fp16 8.98MB][bias 2KB][bufS | b16A | b16B | b32A | b32B] x chunk
    // chunk capped at 32 so the whole ping-pong working set (~140MB) stays
    // Infinity-Cache-resident -> intermediate layers avoid the HBM stream.
    const size_t wqB   = (size_t)NB * WQH * 2;
    const size_t biasB = 2048;
    const size_t hdr   = wqB + biasB;
    const size_t perSlot = (size_t)PXS * 2 * (32 + 16 + 16 + 32 + 32); // 4.33MB
    size_t avail = ws_size > hdr ? ws_size - hdr : 0;
    int chunk = (int)(avail / perSlot);
    if (chunk > 32) chunk = 32;
    if (chunk < 1)  chunk = 1;

    _Float16* wq   = (_Float16*)d_ws;
    float*    bias = (float*)((char*)d_ws + wqB);
    _Float16* bufS = (_Float16*)((char*)d_ws + hdr);
    _Float16* b16A = bufS + (size_t)chunk * PXS * 32;
    _Float16* b16B = b16A + (size_t)chunk * PXS * 16;
    _Float16* b32A = b16B + (size_t)chunk * PXS * 16;
    _Float16* b32B = b32A + (size_t)chunk * PXS * 32;

    prep_w<<<2048, 256, 0, stream>>>(w1, w2, w3, w4, g, be, mu, va, wq, bias);
    zero_b<<<chunk, 256, 0, stream>>>(b16A, b16B, b32A, b32B);

    for (int b0 = 0; b0 < NB; b0 += chunk) {
        int nb = (NB - b0 < chunk) ? (NB - b0) : chunk;
        pad_x<<<nb * 8, 256, 0, stream>>>(x, bufS, b0);
        dim3 g1(16, nb);
        int gc = nb * 32;
        // weight frag-offsets (halves): see prep FO[]*8; bias offsets l*32
        conv3<64,24,1,32,0><<<gc,256,0,stream>>>(bufS, b16A, wq,     0, bias,   0, b0); // L0 10->12 (x @ch12)
        conv3<32, 0,1,32,0><<<gc,256,0,stream>>>(b16A, b16B, wq,  4608, bias,  32, b0); // L1 12->12
        conv3<32, 0,1,64,1><<<gc,256,0,stream>>>(b16B, bufS, wq,  9216, bias,  64, b0); // L2 12->12 -> skip ch0-11
        conv3<64, 0,2,64,0><<<gc,256,0,stream>>>(bufS, b32A, wq, 13824, bias,  96, b0); // L3 22->24
        conv3<64, 0,2,64,0><<<gc,256,0,stream>>>(b32A, b32B, wq, 23040, bias, 128, b0); // L4 24->24
        conv3<64, 0,2,64,1><<<gc,256,0,stream>>>(b32B, bufS, wq, 32256, bias, 160, b0); // L5 24->12 -> skip
        conv3<64, 0,2,64,0><<<gc,256,0,stream>>>(bufS, b32A, wq, 41472, bias, 192, b0); // L6 22->24
        conv3<64, 0,2,64,0><<<gc,256,0,stream>>>(b32A, b32B, wq, 50688, bias, 224, b0); // L7 24->24
        conv3<64, 0,2,64,1><<<gc,256,0,stream>>>(b32B, bufS, wq, 59904, bias, 256, b0); // L8 24->12 -> skip
        conv1<<<g1,256,0,stream>>>(bufS, out, wq, 69120, b0);                           // L9 1x1 22->11
    }
}